// Round 1
// baseline (500.724 us; speedup 1.0000x reference)
//
#include <hip/hip_runtime.h>
#include <hip/hip_bf16.h>
#include <stdint.h>

// ---------------------------------------------------------------------------
// TransformerDecoderBlock on MI355X (gfx950), bf16 MFMA baseline.
// B=2, T=2048, C=1024, H=16, hd=64.  Rows M = B*T = 4096.
// ---------------------------------------------------------------------------

typedef __attribute__((ext_vector_type(8))) short bf16x8;   // 8 bf16 in 4 VGPRs
typedef __attribute__((ext_vector_type(4))) float f32x4;

#define MFMA16(a, b, c) __builtin_amdgcn_mfma_f32_16x16x32_bf16((a), (b), (c), 0, 0, 0)

// --------------------------- transpose + fp32->bf16 ------------------------
// in: fp32 [K, N] row-major  ->  out: bf16 [N, K] row-major
__global__ __launch_bounds__(256) void tconv_k(const float* __restrict__ in,
                                               __hip_bfloat16* __restrict__ out,
                                               int K, int N) {
    __shared__ float tile[32][33];
    const int n0 = blockIdx.x * 32, k0 = blockIdx.y * 32;
    const int tx = threadIdx.x, ty = threadIdx.y;   // block (32, 8)
    for (int i = ty; i < 32; i += 8)
        tile[i][tx] = in[(size_t)(k0 + i) * N + n0 + tx];
    __syncthreads();
    for (int i = ty; i < 32; i += 8)
        out[(size_t)(n0 + i) * K + k0 + tx] = __float2bfloat16(tile[tx][i]);
}

// --------------------------------- layernorm -------------------------------
// x fp32 [rows,1024] -> out bf16 [rows,1024]; one block (256 thr) per row.
__global__ __launch_bounds__(256) void ln_k(const float* __restrict__ x,
                                            const float* __restrict__ g,
                                            const float* __restrict__ beta,
                                            __hip_bfloat16* __restrict__ out) {
    const int row = blockIdx.x;
    const int tid = threadIdx.x;
    float4 v = ((const float4*)(x + (size_t)row * 1024))[tid];
    float s  = v.x + v.y + v.z + v.w;
    float s2 = v.x * v.x + v.y * v.y + v.z * v.z + v.w * v.w;
    for (int off = 1; off < 64; off <<= 1) {
        s  += __shfl_xor(s,  off, 64);
        s2 += __shfl_xor(s2, off, 64);
    }
    __shared__ float ss[4], ss2[4];
    const int w = tid >> 6, lane = tid & 63;
    if (lane == 0) { ss[w] = s; ss2[w] = s2; }
    __syncthreads();
    s  = ss[0] + ss[1] + ss[2] + ss[3];
    s2 = ss2[0] + ss2[1] + ss2[2] + ss2[3];
    const float mu  = s * (1.0f / 1024.0f);
    const float var = s2 * (1.0f / 1024.0f) - mu * mu;
    const float rs  = rsqrtf(var + 1e-5f);
    float4 gv = ((const float4*)g)[tid];
    float4 bv = ((const float4*)beta)[tid];
    __hip_bfloat16* o = out + (size_t)row * 1024 + tid * 4;
    o[0] = __float2bfloat16((v.x - mu) * rs * gv.x + bv.x);
    o[1] = __float2bfloat16((v.y - mu) * rs * gv.y + bv.y);
    o[2] = __float2bfloat16((v.z - mu) * rs * gv.z + bv.z);
    o[3] = __float2bfloat16((v.w - mu) * rs * gv.w + bv.w);
}

// ----------------------------------- GEMM ----------------------------------
// C[M,N] = A[M,K] (bf16, row-major) @ Bt[N,K]^T (bf16, row-major B^T)
//   (+ bias[N]) (relu) (+ resid[M,N] fp32) -> out bf16 or fp32.
// 128x128 block tile, BK=32, 4 waves each 64x64 (4x4 MFMA 16x16x32 tiles).
template <int BIAS, int RELU, int RESID, int OUTBF>
__global__ __launch_bounds__(256, 2) void gemm_k(const __hip_bfloat16* __restrict__ A,
                                                 const __hip_bfloat16* __restrict__ Bt,
                                                 const float* __restrict__ bias,
                                                 const float* __restrict__ resid,
                                                 void* __restrict__ out,
                                                 int M, int N, int K) {
    __align__(16) __shared__ __hip_bfloat16 As[128 * 32];
    __align__(16) __shared__ __hip_bfloat16 Bs[128 * 32];

    const int tid  = threadIdx.x;
    const int lane = tid & 63, w = tid >> 6;
    const int wm = w >> 1, wn = w & 1;            // 2x2 wave grid
    const int m0 = blockIdx.y * 128, n0 = blockIdx.x * 128;
    const int l16 = lane & 15, quad = lane >> 4;

    // staging: each thread moves 32B of A-tile and 32B of B-tile per k-step
    const int srow  = tid >> 1;   // 0..127
    const int shalf = tid & 1;    // which 16-element half of the 32-wide row

    f32x4 acc[4][4] = {};

    for (int k0 = 0; k0 < K; k0 += 32) {
        const uint4* ap = (const uint4*)(A + (size_t)(m0 + srow) * K + k0 + shalf * 16);
        const uint4* bp = (const uint4*)(Bt + (size_t)(n0 + srow) * K + k0 + shalf * 16);
        uint4 a0 = ap[0], a1 = ap[1];
        uint4 b0 = bp[0], b1 = bp[1];
        __syncthreads();   // previous iteration's LDS reads complete
        ((uint4*)As)[srow * 4 + shalf * 2 + 0] = a0;
        ((uint4*)As)[srow * 4 + shalf * 2 + 1] = a1;
        ((uint4*)Bs)[srow * 4 + shalf * 2 + 0] = b0;
        ((uint4*)Bs)[srow * 4 + shalf * 2 + 1] = b1;
        __syncthreads();

        bf16x8 af[4], bf[4];
#pragma unroll
        for (int t = 0; t < 4; t++) {
            af[t] = *(const bf16x8*)(As + (wm * 64 + t * 16 + l16) * 32 + quad * 8);
            bf[t] = *(const bf16x8*)(Bs + (wn * 64 + t * 16 + l16) * 32 + quad * 8);
        }
#pragma unroll
        for (int mt = 0; mt < 4; mt++)
#pragma unroll
            for (int nt = 0; nt < 4; nt++)
                acc[mt][nt] = MFMA16(af[mt], bf[nt], acc[mt][nt]);
    }

    // epilogue: C/D layout is col = lane&15, row = quad*4 + reg
#pragma unroll
    for (int mt = 0; mt < 4; mt++)
#pragma unroll
        for (int nt = 0; nt < 4; nt++) {
            const int row = m0 + wm * 64 + mt * 16 + quad * 4;
            const int col = n0 + wn * 64 + nt * 16 + l16;
            const float bv = BIAS ? bias[col] : 0.0f;
#pragma unroll
            for (int r = 0; r < 4; r++) {
                float v = acc[mt][nt][r] + bv;
                if (RELU) v = v > 0.0f ? v : 0.0f;
                const size_t idx = (size_t)(row + r) * N + col;
                if (RESID) v += resid[idx];
                if (OUTBF) ((__hip_bfloat16*)out)[idx] = __float2bfloat16(v);
                else       ((float*)out)[idx] = v;
            }
        }
}

// ------------------------------ flash attention -----------------------------
// qkv bf16 [B*T, 3072] (q|k|v each 1024 = 16 heads x 64). out bf16 [B*T,1024].
// Block = (head, 64 q rows); 4 waves, each wave owns 16 q rows.
__global__ __launch_bounds__(256, 2) void attn_k(const __hip_bfloat16* __restrict__ qkv,
                                                 __hip_bfloat16* __restrict__ outp) {
    const int T = 2048, C3 = 3072;
    const int bh = blockIdx.y;            // 0..31
    const int b = bh >> 4, h = bh & 15;
    const int qt = blockIdx.x;            // 0..31
    const int q0 = qt * 64;
    const int tid = threadIdx.x, lane = tid & 63, w = tid >> 6;
    const int l16 = lane & 15, quad = lane >> 4;

    __align__(16) __shared__ __hip_bfloat16 Ks[64 * 72];      // [key][d], stride 72
    __align__(16) __shared__ __hip_bfloat16 Vt[64 * 72];      // [d][key], stride 72
    __align__(16) __shared__ __hip_bfloat16 Pw[4][16 * 72];   // per-wave P, stride 72

    // Q fragments (A-operand: m = lane&15 -> q row, k = quad*8+j (+32))
    const int qrow = q0 + w * 16 + l16;
    const __hip_bfloat16* qptr = qkv + (size_t)(b * T + qrow) * C3 + h * 64;
    bf16x8 qf0 = *(const bf16x8*)(qptr + quad * 8);
    bf16x8 qf1 = *(const bf16x8*)(qptr + 32 + quad * 8);

    f32x4 oacc[4] = {};
    float mrow[4], lrow[4];
#pragma unroll
    for (int r = 0; r < 4; r++) { mrow[r] = -3e38f; lrow[r] = 0.0f; }

    const int srow  = tid >> 2;   // 0..63 (key index for staging)
    const int spart = tid & 3;    // 16-element chunk of the 64-wide row

    for (int kt = 0; kt <= qt; kt++) {
        __syncthreads();
        // stage K tile [key][d]
        {
            const __hip_bfloat16* kg =
                qkv + (size_t)(b * T + kt * 64 + srow) * C3 + 1024 + h * 64 + spart * 16;
            uint4 k0v = ((const uint4*)kg)[0];
            uint4 k1v = ((const uint4*)kg)[1];
            *((uint4*)(Ks + srow * 72 + spart * 16) + 0) = k0v;
            *((uint4*)(Ks + srow * 72 + spart * 16) + 1) = k1v;
            // stage V transposed: Vt[d][key]
            const __hip_bfloat16* vg =
                qkv + (size_t)(b * T + kt * 64 + srow) * C3 + 2048 + h * 64 + spart * 16;
#pragma unroll
            for (int j = 0; j < 16; j++)
                Vt[(spart * 16 + j) * 72 + srow] = vg[j];
        }
        __syncthreads();

        // S = (Q K^T) * 1/8  -- 4 key sub-tiles of 16
        f32x4 s[4];
#pragma unroll
        for (int nt = 0; nt < 4; nt++) {
            bf16x8 kf0 = *(const bf16x8*)(Ks + (nt * 16 + l16) * 72 + quad * 8);
            bf16x8 kf1 = *(const bf16x8*)(Ks + (nt * 16 + l16) * 72 + 32 + quad * 8);
            f32x4 z = {};
            z = MFMA16(qf0, kf0, z);
            z = MFMA16(qf1, kf1, z);
            s[nt] = z;
        }

        // scale + causal mask + per-row tile max
        float mt4[4];
#pragma unroll
        for (int r = 0; r < 4; r++) mt4[r] = -3e38f;
#pragma unroll
        for (int nt = 0; nt < 4; nt++) {
            const int col = kt * 64 + nt * 16 + l16;
#pragma unroll
            for (int r = 0; r < 4; r++) {
                const int row = q0 + w * 16 + quad * 4 + r;
                float v = s[nt][r] * 0.125f;
                if (col > row) v = -3e38f;
                s[nt][r] = v;
                mt4[r] = fmaxf(mt4[r], v);
            }
        }
#pragma unroll
        for (int off = 1; off < 16; off <<= 1)
#pragma unroll
            for (int r = 0; r < 4; r++)
                mt4[r] = fmaxf(mt4[r], __shfl_xor(mt4[r], off, 64));

        float mnew[4], alpha[4], ls[4];
#pragma unroll
        for (int r = 0; r < 4; r++) {
            mnew[r] = fmaxf(mrow[r], mt4[r]);
            alpha[r] = __expf(mrow[r] - mnew[r]);
            mrow[r] = mnew[r];
            ls[r] = 0.0f;
        }
        // p = exp(s - m), write P to per-wave LDS (no block barrier needed)
#pragma unroll
        for (int nt = 0; nt < 4; nt++)
#pragma unroll
            for (int r = 0; r < 4; r++) {
                float p = __expf(s[nt][r] - mnew[r]);
                ls[r] += p;
                Pw[w][(quad * 4 + r) * 72 + nt * 16 + l16] = __float2bfloat16(p);
            }
#pragma unroll
        for (int off = 1; off < 16; off <<= 1)
#pragma unroll
            for (int r = 0; r < 4; r++)
                ls[r] += __shfl_xor(ls[r], off, 64);
#pragma unroll
        for (int r = 0; r < 4; r++) lrow[r] = lrow[r] * alpha[r] + ls[r];
#pragma unroll
        for (int dt = 0; dt < 4; dt++)
#pragma unroll
            for (int r = 0; r < 4; r++)
                oacc[dt][r] *= alpha[r];

        asm volatile("s_waitcnt lgkmcnt(0)" ::: "memory");  // P writes visible to own wave

        // O += P @ V  (P as A-operand from Pw; V^T as B-operand from Vt)
        bf16x8 pf0 = *(const bf16x8*)(&Pw[w][l16 * 72 + quad * 8]);
        bf16x8 pf1 = *(const bf16x8*)(&Pw[w][l16 * 72 + 32 + quad * 8]);
#pragma unroll
        for (int dt = 0; dt < 4; dt++) {
            bf16x8 vf0 = *(const bf16x8*)(Vt + (dt * 16 + l16) * 72 + quad * 8);
            bf16x8 vf1 = *(const bf16x8*)(Vt + (dt * 16 + l16) * 72 + 32 + quad * 8);
            oacc[dt] = MFMA16(pf0, vf0, oacc[dt]);
            oacc[dt] = MFMA16(pf1, vf1, oacc[dt]);
        }
    }

    // normalize + write
#pragma unroll
    for (int dt = 0; dt < 4; dt++)
#pragma unroll
        for (int r = 0; r < 4; r++) {
            const int row = q0 + w * 16 + quad * 4 + r;
            const float v = oacc[dt][r] / lrow[r];
            outp[(size_t)(b * T + row) * 1024 + h * 64 + dt * 16 + l16] =
                __float2bfloat16(v);
        }
}

// --------------------------------- launcher --------------------------------
extern "C" void kernel_launch(void* const* d_in, const int* in_sizes, int n_in,
                              void* d_out, int out_size, void* d_ws, size_t ws_size,
                              hipStream_t stream) {
    const float* x     = (const float*)d_in[0];
    const float* Wqkv  = (const float*)d_in[1];
    const float* Wo    = (const float*)d_in[2];
    const float* b_o   = (const float*)d_in[3];
    const float* g1    = (const float*)d_in[4];
    const float* beta1 = (const float*)d_in[5];
    const float* g2    = (const float*)d_in[6];
    const float* beta2 = (const float*)d_in[7];
    const float* Wff1  = (const float*)d_in[8];
    const float* bff1  = (const float*)d_in[9];
    const float* Wff2  = (const float*)d_in[10];
    const float* bff2  = (const float*)d_in[11];

    char* ws = (char*)d_ws;
    size_t off = 0;
    auto alloc = [&](size_t bytes) {
        void* p = ws + off;
        off += (bytes + 255) & ~(size_t)255;
        return p;
    };
    __hip_bfloat16* Wqkv_t = (__hip_bfloat16*)alloc(3072ULL * 1024 * 2);
    __hip_bfloat16* Wo_t   = (__hip_bfloat16*)alloc(1024ULL * 1024 * 2);
    __hip_bfloat16* Wff1_t = (__hip_bfloat16*)alloc(4096ULL * 1024 * 2);
    __hip_bfloat16* Wff2_t = (__hip_bfloat16*)alloc(1024ULL * 4096 * 2);
    __hip_bfloat16* h_bf   = (__hip_bfloat16*)alloc(4096ULL * 1024 * 2);
    __hip_bfloat16* qkv_bf = (__hip_bfloat16*)alloc(4096ULL * 3072 * 2);
    __hip_bfloat16* att_bf = (__hip_bfloat16*)alloc(4096ULL * 1024 * 2);
    float*          x2     = (float*)alloc(4096ULL * 1024 * 4);
    // ff1 activations reuse the (dead by then) qkv+att region: 25.2+8.4 = 33.6 MB
    __hip_bfloat16* ff1_bf = qkv_bf;

    const dim3 tb(32, 8);
    // weights: fp32 [K,N] -> bf16 [N,K]
    tconv_k<<<dim3(3072 / 32, 1024 / 32), tb, 0, stream>>>(Wqkv, Wqkv_t, 1024, 3072);
    tconv_k<<<dim3(1024 / 32, 1024 / 32), tb, 0, stream>>>(Wo,   Wo_t,   1024, 1024);
    tconv_k<<<dim3(4096 / 32, 1024 / 32), tb, 0, stream>>>(Wff1, Wff1_t, 1024, 4096);
    tconv_k<<<dim3(1024 / 32, 4096 / 32), tb, 0, stream>>>(Wff2, Wff2_t, 4096, 1024);

    // h1 = LN1(x)
    ln_k<<<4096, 256, 0, stream>>>(x, g1, beta1, h_bf);
    // qkv = h1 @ Wqkv
    gemm_k<0, 0, 0, 1><<<dim3(3072 / 128, 4096 / 128), 256, 0, stream>>>(
        h_bf, Wqkv_t, nullptr, nullptr, qkv_bf, 4096, 3072, 1024);
    // attention
    attn_k<<<dim3(32, 32), 256, 0, stream>>>(qkv_bf, att_bf);
    // x2 = x + att @ Wo + b_o   (fp32)
    gemm_k<1, 0, 1, 0><<<dim3(1024 / 128, 4096 / 128), 256, 0, stream>>>(
        att_bf, Wo_t, b_o, x, x2, 4096, 1024, 1024);
    // h2 = LN2(x2)
    ln_k<<<4096, 256, 0, stream>>>(x2, g2, beta2, h_bf);
    // ff1 = relu(h2 @ Wff1 + b_ff1)
    gemm_k<1, 1, 0, 1><<<dim3(4096 / 128, 4096 / 128), 256, 0, stream>>>(
        h_bf, Wff1_t, bff1, nullptr, ff1_bf, 4096, 4096, 1024);
    // out = x2 + ff1 @ Wff2 + b_ff2  (fp32)
    gemm_k<1, 0, 1, 0><<<dim3(1024 / 128, 4096 / 128), 256, 0, stream>>>(
        ff1_bf, Wff2_t, bff2, x2, (float*)d_out, 4096, 1024, 4096);
}